// Round 7
// baseline (818.484 us; speedup 1.0000x reference)
//
#include <hip/hip_runtime.h>
#include <hip/hip_bf16.h>

typedef short bf16x8 __attribute__((ext_vector_type(8)));
typedef float f32x4 __attribute__((ext_vector_type(4)));
typedef unsigned short u16;

__device__ __forceinline__ float bf2f(u16 u) {
    union { unsigned int i; float f; } x; x.i = ((unsigned int)u) << 16; return x.f;
}
__device__ __forceinline__ u16 f2bf(float f) {
    union { float f; unsigned int i; } x; x.f = f;
    unsigned int r = x.i + 0x7fff + ((x.i >> 16) & 1);
    return (u16)(r >> 16);
}
__device__ __forceinline__ f32x4 mfma16(bf16x8 a, bf16x8 b, f32x4 c) {
    return __builtin_amdgcn_mfma_f32_16x16x32_bf16(a, b, c, 0, 0, 0);
}

// ------------- transpose fp32 [R][C] -> bf16 [C][R] ---------------------
__global__ __launch_bounds__(256)
void transpose_kernel(const float* __restrict__ in, u16* __restrict__ out, int R, int C) {
    __shared__ float t[32][33];
    const int c0 = blockIdx.x * 32, r0 = blockIdx.y * 32;
    const int tx = threadIdx.x & 31, ty = threadIdx.x >> 5; // ty 0..7
#pragma unroll
    for (int i = 0; i < 32; i += 8) t[ty + i][tx] = in[(size_t)(r0 + ty + i) * C + c0 + tx];
    __syncthreads();
#pragma unroll
    for (int i = 0; i < 32; i += 8) out[(size_t)(c0 + ty + i) * R + r0 + tx] = f2bf(t[tx][ty + i]);
}

// ------------- fp32 -> bf16 convert (8 elems/thread) --------------------
__global__ __launch_bounds__(256)
void convert_kernel(const float* __restrict__ in, u16* __restrict__ out) {
    const size_t i = ((size_t)blockIdx.x * 256 + threadIdx.x) * 8;
    const float4 a = *(const float4*)(in + i);
    const float4 b = *(const float4*)(in + i + 4);
    bf16x8 o;
    o[0] = (short)f2bf(a.x); o[1] = (short)f2bf(a.y);
    o[2] = (short)f2bf(a.z); o[3] = (short)f2bf(a.w);
    o[4] = (short)f2bf(b.x); o[5] = (short)f2bf(b.y);
    o[6] = (short)f2bf(b.z); o[7] = (short)f2bf(b.w);
    *(bf16x8*)(out + i) = o;
}

// ------------- positional embedding pe[2048][1024] (bf16) ---------------
__global__ __launch_bounds__(256)
void pe_kernel(u16* __restrict__ pe) {
    const int idx = blockIdx.x * 256 + threadIdx.x; // 2M elements
    const int p = idx >> 10, d = idx & 1023;
    const float pos = (float)(2047 - p);
    const int k = d & 511;
    const float invf = powf(10000.f, ((float)(2 * k)) * (-1.f / 1024.f));
    const float a = pos * invf;
    pe[idx] = f2bf((d < 512) ? sinf(a) : cosf(a));
}

// ------------- LayerNorm (fp32 in, bf16 out), one wave per row ----------
__global__ __launch_bounds__(256)
void ln_kernel(const float* __restrict__ inp, const float* __restrict__ gg,
               const float* __restrict__ bb, u16* __restrict__ outp) {
    const int row = blockIdx.x * 4 + (threadIdx.x >> 6);
    const int l = threadIdx.x & 63;
    const size_t base = (size_t)row * 1024 + l * 16;
    float v[16];
    const float4* p4 = (const float4*)(inp + base);
#pragma unroll
    for (int j = 0; j < 4; ++j) {
        float4 f = p4[j];
        v[j*4+0] = f.x; v[j*4+1] = f.y; v[j*4+2] = f.z; v[j*4+3] = f.w;
    }
    float s = 0.f, s2 = 0.f;
#pragma unroll
    for (int j = 0; j < 16; ++j) { s += v[j]; s2 += v[j] * v[j]; }
#pragma unroll
    for (int off = 1; off < 64; off <<= 1) {
        s += __shfl_xor(s, off, 64);
        s2 += __shfl_xor(s2, off, 64);
    }
    const float mu = s * 0.0009765625f;
    const float var = s2 * 0.0009765625f - mu * mu;
    const float rs = rsqrtf(var + 1e-5f);
#pragma unroll
    for (int j = 0; j < 16; ++j)
        outp[base + j] = f2bf((v[j] - mu) * rs * gg[l * 16 + j] + bb[l * 16 + j]);
}

// ---------------- GEMM: C[M][N] = A[M][K] @ W[K][N], Wt = W^T [N][K] ----
// 128x128 tile, 4 waves (2x2), 16x16x32 bf16 MFMA, BK=32, reg-staged LDS.
// EPI: 0 plain bf16; 1 dual out +colbias (qu/qv); 2 +fp32 resid -> f32 out;
//      3 +colbias, exact GELU -> bf16; 4 +colbias +f32 resid -> F32 out.
template<int EPI, bool CATA>
__global__ __launch_bounds__(256)
void gemm_kernel(const u16* __restrict__ A, const u16* __restrict__ A2,
                 const u16* __restrict__ Wt, void* __restrict__ outp,
                 u16* __restrict__ out2, const float* __restrict__ cb1,
                 const float* __restrict__ cb2, const float* __restrict__ residp,
                 int Mdim, int Ndim, int Kdim) {
    __shared__ u16 As[128 * 32];
    __shared__ u16 Bs[128 * 32];
    const int tid = threadIdx.x;
    const int w = tid >> 6, l = tid & 63;
    const int wr = w >> 1, wc = w & 1;
    const int m0 = blockIdx.x * 128, n0 = blockIdx.y * 128;
    f32x4 acc[4][4] = {};

    for (int k0 = 0; k0 < Kdim; k0 += 32) {
        __syncthreads();
#pragma unroll
        for (int p = 0; p < 2; ++p) {
            const int e = ((p * 4 + w) * 64 + l) * 8;
            const int row = e >> 5, colk = e & 31;
            const u16* srcA;
            if (CATA) { // rows: [memb(1024) ; xn(1024)] per batch, K=1024
                const int rr = m0 + row;
                const int bb_ = rr >> 11, pos = rr & 2047;
                srcA = (pos < 1024 ? A + ((size_t)(bb_ * 1024 + pos)) * 1024
                                   : A2 + ((size_t)(bb_ * 1024 + pos - 1024)) * 1024)
                       + (k0 + colk);
            } else {
                srcA = A + (size_t)(m0 + row) * Kdim + (k0 + colk);
            }
            *(bf16x8*)&As[e] = *(const bf16x8*)srcA;
            *(bf16x8*)&Bs[e] = *(const bf16x8*)(Wt + (size_t)(n0 + row) * Kdim + (k0 + colk));
        }
        __syncthreads();
        bf16x8 af[4], bfr[4];
#pragma unroll
        for (int mi = 0; mi < 4; ++mi)
            af[mi] = *(const bf16x8*)&As[(wr * 64 + mi * 16 + (l & 15)) * 32 + (l >> 4) * 8];
#pragma unroll
        for (int ni = 0; ni < 4; ++ni)
            bfr[ni] = *(const bf16x8*)&Bs[(wc * 64 + ni * 16 + (l & 15)) * 32 + (l >> 4) * 8];
#pragma unroll
        for (int mi = 0; mi < 4; ++mi)
#pragma unroll
            for (int ni = 0; ni < 4; ++ni)
                acc[mi][ni] = mfma16(af[mi], bfr[ni], acc[mi][ni]);
    }

#pragma unroll
    for (int mi = 0; mi < 4; ++mi)
#pragma unroll
        for (int ni = 0; ni < 4; ++ni)
#pragma unroll
            for (int rg = 0; rg < 4; ++rg) {
                const int row = m0 + wr * 64 + mi * 16 + (l >> 4) * 4 + rg;
                const int col = n0 + wc * 64 + ni * 16 + (l & 15);
                const size_t idx = (size_t)row * Ndim + col;
                const float v = acc[mi][ni][rg];
                if (EPI == 0) {
                    ((u16*)outp)[idx] = f2bf(v);
                } else if (EPI == 1) {
                    ((u16*)outp)[idx] = f2bf(v + cb1[col]);
                    out2[idx] = f2bf(v + cb2[col]);
                } else if (EPI == 2) {
                    ((float*)outp)[idx] = v + residp[idx];
                } else if (EPI == 3) {
                    const float t = v + cb1[col];
                    ((u16*)outp)[idx] = f2bf(0.5f * t * (1.f + erff(t * 0.70710678118654752f)));
                } else {
                    ((float*)outp)[idx] = v + cb1[col] + residp[idx]; // fp32 y
                }
            }
}

// ---------------- fused rel-attention (flash-style) ---------------------
// grid: B*H*(T/64) blocks, 256 threads (4 waves x 16 q-rows).
// scores = (qu.k + relshift(qv.r)) / 8 ; softmax over L=2048 (NO mask) ; P@V.
__global__ __launch_bounds__(256)
void attn_kernel(const u16* __restrict__ qu, const u16* __restrict__ qv,
                 const u16* __restrict__ kcat, const u16* __restrict__ vcat,
                 const u16* __restrict__ rbuf, u16* __restrict__ outp) {
    constexpr int T = 1024, L = 2048, MM = 1024;
    __shared__ u16 Vt[2][64][72]; // V^T tile: [dh][j], double buffered
    __shared__ u16 Pl[4][16][72]; // per-wave P tile [row][j]
    const int bid = blockIdx.x;
    const int it = bid & 15, h = (bid >> 4) & 15, b = bid >> 8;
    const int i0 = it * 64;
    const int w = threadIdx.x >> 6, l = threadIdx.x & 63;
    const int lg = l >> 4, ll = l & 15;
    const int iw0 = i0 + w * 16;

    bf16x8 quf[2], qvf[2], qv2f[2];
    {
        const size_t qrow = (size_t)(b * T + iw0 + ll);
        const int qc = h * 64 + lg * 8;
        quf[0] = *(const bf16x8*)&qu[qrow * 1024 + qc];
        quf[1] = *(const bf16x8*)&qu[qrow * 1024 + qc + 32];
        qvf[0] = *(const bf16x8*)&qv[qrow * 1024 + qc];
        qvf[1] = *(const bf16x8*)&qv[qrow * 1024 + qc + 32];
        const int r2 = iw0 + ll + 1;
        const size_t qrow2 = (size_t)(b * T + (r2 < T ? r2 : T - 1));
        qv2f[0] = *(const bf16x8*)&qv[qrow2 * 1024 + qc];
        qv2f[1] = *(const bf16x8*)&qv[qrow2 * 1024 + qc + 32];
    }
    const u16* kb = kcat + (size_t)b * L * 1024 + h * 64;
    const u16* vb = vcat + (size_t)b * L * 1024 + h * 64;
    const u16* rb = rbuf + h * 64;

    f32x4 o_acc[4] = {};
    float m_run[4] = {-1e30f, -1e30f, -1e30f, -1e30f};
    float l_run[4] = {0.f, 0.f, 0.f, 0.f};
    const bf16x8 zv = {0, 0, 0, 0, 0, 0, 0, 0};
    const int vjj = threadIdx.x & 63, vdg = threadIdx.x >> 6;

    for (int jt = 0; jt < 32; ++jt) {
        const int j0 = jt * 64;
        const int buf = jt & 1;
        { // stage V^T cooperatively
            const u16* src = vb + (size_t)(j0 + vjj) * 1024 + vdg * 16;
            bf16x8 v0 = *(const bf16x8*)src;
            bf16x8 v1 = *(const bf16x8*)(src + 8);
#pragma unroll
            for (int c = 0; c < 8; ++c) {
                Vt[buf][vdg * 16 + c][vjj] = (u16)v0[c];
                Vt[buf][vdg * 16 + 8 + c][vjj] = (u16)v1[c];
            }
        }
        __syncthreads();

        // content: S = Qu @ K^T  (16 rows x 64 cols per wave)
        f32x4 sacc[4];
#pragma unroll
        for (int ns = 0; ns < 4; ++ns) {
            f32x4 a = {0.f, 0.f, 0.f, 0.f};
            const u16* kp = kb + (size_t)(j0 + ns * 16 + ll) * 1024 + lg * 8;
            a = mfma16(quf[0], *(const bf16x8*)kp, a);
            a = mfma16(quf[1], *(const bf16x8*)(kp + 32), a);
            sacc[ns] = a;
        }

        // rel bands: G[i, c] = qv[i] . r[m0 + c] (80-wide), same for wrap
        const bool need_main = (j0 <= MM + iw0 + 15);
        const bool need_wrap = (j0 + 63 >= MM + iw0 + 2);
        f32x4 g[5] = {}; f32x4 g2[5] = {};
        if (need_main) {
            const int m0 = j0 + T - iw0 - 16;
#pragma unroll
            for (int cs = 0; cs < 5; ++cs) {
                const int m = m0 + cs * 16 + ll;
                bf16x8 b0 = zv, b1 = zv;
                if (m >= 0 && m < L) {
                    const u16* rp = rb + (size_t)m * 1024 + lg * 8;
                    b0 = *(const bf16x8*)rp; b1 = *(const bf16x8*)(rp + 32);
                }
                f32x4 a = {0.f, 0.f, 0.f, 0.f};
                a = mfma16(qvf[0], b0, a);
                a = mfma16(qvf[1], b1, a);
                g[cs] = a;
            }
        }
        if (need_wrap) {
            const int m0w = j0 - MM - iw0 - 17;
#pragma unroll
            for (int cs = 0; cs < 5; ++cs) {
                const int m = m0w + cs * 16 + ll;
                bf16x8 b0 = zv, b1 = zv;
                if (m >= 0 && m < L) {
                    const u16* rp = rb + (size_t)m * 1024 + lg * 8;
                    b0 = *(const bf16x8*)rp; b1 = *(const bf16x8*)(rp + 32);
                }
                f32x4 a = {0.f, 0.f, 0.f, 0.f};
                a = mfma16(qv2f[0], b0, a);
                a = mfma16(qv2f[1], b1, a);
                g2[cs] = a;
            }
        }

        // assemble scores + online softmax + write P
#pragma unroll
        for (int r = 0; r < 4; ++r) {
            const int i_loc = lg * 4 + r;
            const int ig = iw0 + i_loc;
            float sv[4];
#pragma unroll
            for (int ns = 0; ns < 4; ++ns) {
                const int j_loc = ns * 16 + ll;
                const int c = j_loc + 15 - i_loc; // diagonal band column
                const int srcl = (l & 48) | (c & 15);
                float gm = 0.f, gw = 0.f;
                if (need_main) {
                    const float t0 = __shfl(g[ns][r], srcl, 64);
                    const float t1 = __shfl(g[ns + 1][r], srcl, 64);
                    gm = ((c >> 4) == ns) ? t0 : t1;
                }
                if (need_wrap) {
                    const float t0 = __shfl(g2[ns][r], srcl, 64);
                    const float t1 = __shfl(g2[ns + 1][r], srcl, 64);
                    gw = ((c >> 4) == ns) ? t0 : t1;
                }
                const int jg = j0 + j_loc;
                const float rel = (jg <= MM + ig) ? gm : ((jg == MM + ig + 1) ? 0.f : gw);
                sv[ns] = (sacc[ns][r] + rel) * 0.125f;
            }
            float pm = fmaxf(fmaxf(sv[0], sv[1]), fmaxf(sv[2], sv[3]));
            pm = fmaxf(pm, __shfl_xor(pm, 1, 64));
            pm = fmaxf(pm, __shfl_xor(pm, 2, 64));
            pm = fmaxf(pm, __shfl_xor(pm, 4, 64));
            pm = fmaxf(pm, __shfl_xor(pm, 8, 64));
            const float mnew = fmaxf(m_run[r], pm);
            const float alpha = __expf(m_run[r] - mnew);
            float ps = 0.f;
#pragma unroll
            for (int ns = 0; ns < 4; ++ns) {
                const float p = __expf(sv[ns] - mnew);
                ps += p;
                Pl[w][i_loc][ns * 16 + ll] = f2bf(p);
            }
            ps += __shfl_xor(ps, 1, 64);
            ps += __shfl_xor(ps, 2, 64);
            ps += __shfl_xor(ps, 4, 64);
            ps += __shfl_xor(ps, 8, 64);
            l_run[r] = l_run[r] * alpha + ps;
            m_run[r] = mnew;
#pragma unroll
            for (int ns = 0; ns < 4; ++ns) o_acc[ns][r] *= alpha;
        }

        // O += P @ V
        const bf16x8 ap0 = *(const bf16x8*)&Pl[w][ll][lg * 8];
        const bf16x8 ap1 = *(const bf16x8*)&Pl[w][ll][32 + lg * 8];
#pragma unroll
        for (int ns = 0; ns < 4; ++ns) {
            const bf16x8 bv0 = *(const bf16x8*)&Vt[buf][ns * 16 + ll][lg * 8];
            const bf16x8 bv1 = *(const bf16x8*)&Vt[buf][ns * 16 + ll][32 + lg * 8];
            o_acc[ns] = mfma16(ap0, bv0, o_acc[ns]);
            o_acc[ns] = mfma16(ap1, bv1, o_acc[ns]);
        }
    }

#pragma unroll
    for (int ns = 0; ns < 4; ++ns)
#pragma unroll
        for (int r = 0; r < 4; ++r) {
            const int row = iw0 + lg * 4 + r;
            outp[(size_t)(b * T + row) * 1024 + h * 64 + ns * 16 + ll] =
                f2bf(o_acc[ns][r] / l_run[r]);
        }
}

// ------------------------------- launch ---------------------------------
extern "C" void kernel_launch(void* const* d_in, const int* in_sizes, int n_in,
                              void* d_out, int out_size, void* d_ws, size_t ws_size,
                              hipStream_t stream) {
    // Inputs fp32 (reference dtypes); outputs fp32 (reference output dtype).
    const float* x    = (const float*)d_in[0];
    const float* mem  = (const float*)d_in[1];
    const float* Wq   = (const float*)d_in[2];
    const float* Wk   = (const float*)d_in[3];
    const float* Wv   = (const float*)d_in[4];
    const float* Wr   = (const float*)d_in[5];
    const float* Wo   = (const float*)d_in[6];
    const float* bu   = (const float*)d_in[7];
    const float* bv   = (const float*)d_in[8];
    const float* ln1g = (const float*)d_in[9];
    const float* ln1b = (const float*)d_in[10];
    const float* ln2g = (const float*)d_in[11];
    const float* ln2b = (const float*)d_in[12];
    const float* W1   = (const float*)d_in[13];
    const float* b1   = (const float*)d_in[14];
    const float* W2   = (const float*)d_in[15];
    const float* b2   = (const float*)d_in[16];

    float* y_out   = (float*)d_out;             // [4,1024,1024] fp32, step 9
    float* mem_out = (float*)d_out + 4194304;   // new_mem = x (fp32), step 6.5

    // ===== d_out (32 MB fp32) as scratch, time-multiplexed =====
    // bytes [0,8):   attno [5,6]            -> y fp32 [9] spans [0,16)
    // bytes [8,12):  pe [1,2)
    // bytes [12,16): rbuf [2,5]
    // bytes [16,26): WqT,WkT,WvT,WrT,WoT [1..6] -> mem_out fp32 [6.5,end) spans [16,32)
    char* dob = (char*)d_out;
    u16* attno = (u16*)(dob + 0);
    u16* pe    = (u16*)(dob + (size_t)8  * 1048576);
    u16* rbuf  = (u16*)(dob + (size_t)12 * 1048576);
    u16* WqT   = (u16*)(dob + (size_t)16 * 1048576);
    u16* WkT   = (u16*)(dob + (size_t)18 * 1048576);
    u16* WvT   = (u16*)(dob + (size_t)20 * 1048576);
    u16* WrT   = (u16*)(dob + (size_t)22 * 1048576);
    u16* WoT   = (u16*)(dob + (size_t)24 * 1048576);

    // ===== ws layout, extent 64 MB =====
    // [0,8):   xn [1,4]     -> x2n [7,8]   -> W2T [8.5,9]
    // [8,24):  qu [3,5] @ [8,16), qv [3,5] @ [16,24) -> x2f fp32 [6,9]
    // [24,56): kcat [4,5] @ [24,40), vcat [4,5] @ [40,56) -> ffh [8,9]
    // [56,64): memb [1,4]   -> W1T [6.5,8]
    char* ws = (char*)d_ws;
    const size_t MB = 1u << 20;
    u16*  xn    = (u16*)(ws + 0 * MB);
    u16*  x2n   = (u16*)(ws + 0 * MB);
    u16*  W2T   = (u16*)(ws + 0 * MB);
    u16*  qu    = (u16*)(ws + 8 * MB);
    float* x2f  = (float*)(ws + 8 * MB);
    u16*  qv    = (u16*)(ws + 16 * MB);
    u16*  kcat  = (u16*)(ws + 24 * MB);
    u16*  ffh   = (u16*)(ws + 24 * MB);
    u16*  vcat  = (u16*)(ws + 40 * MB);
    u16*  memb  = (u16*)(ws + 56 * MB);
    u16*  W1T   = (u16*)(ws + 56 * MB);

    // step 1: weight transposes (fp32 -> bf16 W^T), pe, mem convert, LN1
    transpose_kernel<<<dim3(32, 32), 256, 0, stream>>>(Wq, WqT, 1024, 1024);
    transpose_kernel<<<dim3(32, 32), 256, 0, stream>>>(Wk, WkT, 1024, 1024);
    transpose_kernel<<<dim3(32, 32), 256, 0, stream>>>(Wv, WvT, 1024, 1024);
    transpose_kernel<<<dim3(32, 32), 256, 0, stream>>>(Wr, WrT, 1024, 1024);
    transpose_kernel<<<dim3(32, 32), 256, 0, stream>>>(Wo, WoT, 1024, 1024);
    pe_kernel<<<8192, 256, 0, stream>>>(pe);
    convert_kernel<<<2048, 256, 0, stream>>>(mem, memb);
    ln_kernel<<<1024, 256, 0, stream>>>(x, ln1g, ln1b, xn);
    // step 2: r = pe @ Wr
    gemm_kernel<0, false><<<dim3(16, 8), 256, 0, stream>>>(pe, nullptr, WrT, rbuf, nullptr, nullptr, nullptr, nullptr, 2048, 1024, 1024);
    // step 3: qu/qv = xn @ Wq (+bias_u / +bias_v)
    gemm_kernel<1, false><<<dim3(32, 8), 256, 0, stream>>>(xn, nullptr, WqT, qu, qv, bu, bv, nullptr, 4096, 1024, 1024);
    // step 4: k/v = [memb; xn] @ Wk/Wv
    gemm_kernel<0, true><<<dim3(64, 8), 256, 0, stream>>>(memb, xn, WkT, kcat, nullptr, nullptr, nullptr, nullptr, 8192, 1024, 1024);
    gemm_kernel<0, true><<<dim3(64, 8), 256, 0, stream>>>(memb, xn, WvT, vcat, nullptr, nullptr, nullptr, nullptr, 8192, 1024, 1024);
    // step 5: fused attention -> attno (d_out bytes [0,8); pe area untouched)
    attn_kernel<<<1024, 256, 0, stream>>>(qu, qv, kcat, vcat, rbuf, attno);
    // step 6: x2 = x + attn @ Wo (fp32; x2f overlays dead qu/qv)
    gemm_kernel<2, false><<<dim3(32, 8), 256, 0, stream>>>(attno, nullptr, WoT, x2f, nullptr, nullptr, nullptr, x, 4096, 1024, 1024);
    // step 6.5: W1T into memb slot (memb dead); new_mem = x (fp32 copy,
    //           clobbers WqT..WoT which are all dead after step 6)
    transpose_kernel<<<dim3(128, 32), 256, 0, stream>>>(W1, W1T, 1024, 4096);
    hipMemcpyAsync(mem_out, x, (size_t)4194304 * 4, hipMemcpyDeviceToDevice, stream);
    // step 7: LN2 (x2n overlays xn; xn dead)
    ln_kernel<<<1024, 256, 0, stream>>>(x2f, ln2g, ln2b, x2n);
    // step 8: ffh = gelu(x2n @ W1 + b1)  (ffh overlays dead kcat/vcat)
    gemm_kernel<3, false><<<dim3(32, 32), 256, 0, stream>>>(x2n, nullptr, W1T, ffh, nullptr, b1, nullptr, nullptr, 4096, 4096, 1024);
    // step 8.5: W2T into x2n slot (x2n dead after step 8)
    transpose_kernel<<<dim3(32, 128), 256, 0, stream>>>(W2, W2T, 4096, 1024);
    // step 9: y = x2 + ffh @ W2 + b2 (fp32 out; clobbers attno/pe/rbuf, all dead)
    gemm_kernel<4, false><<<dim3(32, 8), 256, 0, stream>>>(ffh, nullptr, W2T, y_out, nullptr, b2, nullptr, x2f, 4096, 1024, 4096);
    (void)in_sizes; (void)n_in; (void)out_size; (void)ws_size;
}

// Round 8
// 712.238 us; speedup vs baseline: 1.1492x; 1.1492x over previous
//
#include <hip/hip_runtime.h>
#include <hip/hip_bf16.h>

typedef short bf16x8 __attribute__((ext_vector_type(8)));
typedef float f32x4 __attribute__((ext_vector_type(4)));
typedef unsigned short u16;

__device__ __forceinline__ float bf2f(u16 u) {
    union { unsigned int i; float f; } x; x.i = ((unsigned int)u) << 16; return x.f;
}
__device__ __forceinline__ u16 f2bf(float f) {
    union { float f; unsigned int i; } x; x.f = f;
    unsigned int r = x.i + 0x7fff + ((x.i >> 16) & 1);
    return (u16)(r >> 16);
}
__device__ __forceinline__ f32x4 mfma16(bf16x8 a, bf16x8 b, f32x4 c) {
    return __builtin_amdgcn_mfma_f32_16x16x32_bf16(a, b, c, 0, 0, 0);
}
#define GLL16(lds_base, gsrc) \
    __builtin_amdgcn_global_load_lds((const __attribute__((address_space(1))) void*)(gsrc), \
                                     (__attribute__((address_space(3))) void*)(lds_base), 16, 0, 0)

// ------------- transpose fp32 [R][C] -> bf16 [C][R] ---------------------
__global__ __launch_bounds__(256)
void transpose_kernel(const float* __restrict__ in, u16* __restrict__ out, int R, int C) {
    __shared__ float t[32][33];
    const int c0 = blockIdx.x * 32, r0 = blockIdx.y * 32;
    const int tx = threadIdx.x & 31, ty = threadIdx.x >> 5; // ty 0..7
#pragma unroll
    for (int i = 0; i < 32; i += 8) t[ty + i][tx] = in[(size_t)(r0 + ty + i) * C + c0 + tx];
    __syncthreads();
#pragma unroll
    for (int i = 0; i < 32; i += 8) out[(size_t)(c0 + ty + i) * R + r0 + tx] = f2bf(t[tx][ty + i]);
}

// ------------- fp32 -> bf16 convert (8 elems/thread) --------------------
__global__ __launch_bounds__(256)
void convert_kernel(const float* __restrict__ in, u16* __restrict__ out) {
    const size_t i = ((size_t)blockIdx.x * 256 + threadIdx.x) * 8;
    const float4 a = *(const float4*)(in + i);
    const float4 b = *(const float4*)(in + i + 4);
    bf16x8 o;
    o[0] = (short)f2bf(a.x); o[1] = (short)f2bf(a.y);
    o[2] = (short)f2bf(a.z); o[3] = (short)f2bf(a.w);
    o[4] = (short)f2bf(b.x); o[5] = (short)f2bf(b.y);
    o[6] = (short)f2bf(b.z); o[7] = (short)f2bf(b.w);
    *(bf16x8*)(out + i) = o;
}

// ------------- positional embedding pe[2048][1024] (bf16) ---------------
__global__ __launch_bounds__(256)
void pe_kernel(u16* __restrict__ pe) {
    const int idx = blockIdx.x * 256 + threadIdx.x; // 2M elements
    const int p = idx >> 10, d = idx & 1023;
    const float pos = (float)(2047 - p);
    const int k = d & 511;
    const float invf = powf(10000.f, ((float)(2 * k)) * (-1.f / 1024.f));
    const float a = pos * invf;
    pe[idx] = f2bf((d < 512) ? sinf(a) : cosf(a));
}

// ------------- LayerNorm (fp32 in, bf16 out), one wave per row ----------
__global__ __launch_bounds__(256)
void ln_kernel(const float* __restrict__ inp, const float* __restrict__ gg,
               const float* __restrict__ bb, u16* __restrict__ outp) {
    const int row = blockIdx.x * 4 + (threadIdx.x >> 6);
    const int l = threadIdx.x & 63;
    const size_t base = (size_t)row * 1024 + l * 16;
    float v[16];
    const float4* p4 = (const float4*)(inp + base);
#pragma unroll
    for (int j = 0; j < 4; ++j) {
        float4 f = p4[j];
        v[j*4+0] = f.x; v[j*4+1] = f.y; v[j*4+2] = f.z; v[j*4+3] = f.w;
    }
    float s = 0.f, s2 = 0.f;
#pragma unroll
    for (int j = 0; j < 16; ++j) { s += v[j]; s2 += v[j] * v[j]; }
#pragma unroll
    for (int off = 1; off < 64; off <<= 1) {
        s += __shfl_xor(s, off, 64);
        s2 += __shfl_xor(s2, off, 64);
    }
    const float mu = s * 0.0009765625f;
    const float var = s2 * 0.0009765625f - mu * mu;
    const float rs = rsqrtf(var + 1e-5f);
#pragma unroll
    for (int j = 0; j < 16; ++j)
        outp[base + j] = f2bf((v[j] - mu) * rs * gg[l * 16 + j] + bb[l * 16 + j]);
}

// ---------------- GEMM: C[M][N] = A[M][K] @ W[K][N], Wt = W^T [N][K] ----
// 128x128 tile, 4 waves (2x2), 16x16x32 bf16 MFMA, BK=32.
// Staging via global_load_lds width=16 (m97 pattern).
// EPI: 0 plain bf16; 1 dual out +colbias (qu/qv); 2 +fp32 resid -> f32 out;
//      3 +colbias, exact GELU -> bf16; 4 +colbias +f32 resid -> F32 out.
template<int EPI, bool CATA>
__global__ __launch_bounds__(256)
void gemm_kernel(const u16* __restrict__ A, const u16* __restrict__ A2,
                 const u16* __restrict__ Wt, void* __restrict__ outp,
                 u16* __restrict__ out2, const float* __restrict__ cb1,
                 const float* __restrict__ cb2, const float* __restrict__ residp,
                 int Mdim, int Ndim, int Kdim) {
    __shared__ __attribute__((aligned(16))) u16 As[128 * 32];
    __shared__ __attribute__((aligned(16))) u16 Bs[128 * 32];
    const int tid = threadIdx.x;
    const int w = tid >> 6, l = tid & 63;
    const int wr = w >> 1, wc = w & 1;
    const int m0 = blockIdx.x * 128, n0 = blockIdx.y * 128;
    f32x4 acc[4][4] = {};

    for (int k0 = 0; k0 < Kdim; k0 += 32) {
        __syncthreads();
#pragma unroll
        for (int p = 0; p < 2; ++p) {
            const int ebase = (p * 4 + w) * 512;      // wave-uniform LDS base (u16 idx)
            const int e = ebase + l * 8;              // this lane's element
            const int row = e >> 5, colk = e & 31;
            const u16* srcA;
            if (CATA) { // rows: [memb(1024) ; xn(1024)] per batch, K=1024
                const int rr = m0 + row;
                const int bb_ = rr >> 11, pos = rr & 2047;
                srcA = (pos < 1024 ? A + ((size_t)(bb_ * 1024 + pos)) * 1024
                                   : A2 + ((size_t)(bb_ * 1024 + pos - 1024)) * 1024)
                       + (k0 + colk);
            } else {
                srcA = A + (size_t)(m0 + row) * Kdim + (k0 + colk);
            }
            const u16* srcB = Wt + (size_t)(n0 + row) * Kdim + (k0 + colk);
            GLL16(&As[ebase], srcA);
            GLL16(&Bs[ebase], srcB);
        }
        __syncthreads();
        bf16x8 af[4], bfr[4];
#pragma unroll
        for (int mi = 0; mi < 4; ++mi)
            af[mi] = *(const bf16x8*)&As[(wr * 64 + mi * 16 + (l & 15)) * 32 + (l >> 4) * 8];
#pragma unroll
        for (int ni = 0; ni < 4; ++ni)
            bfr[ni] = *(const bf16x8*)&Bs[(wc * 64 + ni * 16 + (l & 15)) * 32 + (l >> 4) * 8];
#pragma unroll
        for (int mi = 0; mi < 4; ++mi)
#pragma unroll
            for (int ni = 0; ni < 4; ++ni)
                acc[mi][ni] = mfma16(af[mi], bfr[ni], acc[mi][ni]);
    }

#pragma unroll
    for (int mi = 0; mi < 4; ++mi)
#pragma unroll
        for (int ni = 0; ni < 4; ++ni)
#pragma unroll
            for (int rg = 0; rg < 4; ++rg) {
                const int row = m0 + wr * 64 + mi * 16 + (l >> 4) * 4 + rg;
                const int col = n0 + wc * 64 + ni * 16 + (l & 15);
                const size_t idx = (size_t)row * Ndim + col;
                const float v = acc[mi][ni][rg];
                if (EPI == 0) {
                    ((u16*)outp)[idx] = f2bf(v);
                } else if (EPI == 1) {
                    ((u16*)outp)[idx] = f2bf(v + cb1[col]);
                    out2[idx] = f2bf(v + cb2[col]);
                } else if (EPI == 2) {
                    ((float*)outp)[idx] = v + residp[idx];
                } else if (EPI == 3) {
                    const float t = v + cb1[col];
                    ((u16*)outp)[idx] = f2bf(0.5f * t * (1.f + erff(t * 0.70710678118654752f)));
                } else {
                    ((float*)outp)[idx] = v + cb1[col] + residp[idx]; // fp32 y
                }
            }
}

// ---------------- fused rel-attention (flash-style) ---------------------
// grid: 1024 blocks (XCD-swizzled), 256 threads (4 waves x 16 q-rows).
// scores = (qu.k + relshift(qv.r)) / 8 ; softmax over L=2048 (NO mask) ; P@V.
// Sequential band processing (main then wrap) to cut register pressure.
__global__ __launch_bounds__(256, 2)
void attn_kernel(const u16* __restrict__ qu, const u16* __restrict__ qv,
                 const u16* __restrict__ kcat, const u16* __restrict__ vcat,
                 const u16* __restrict__ rbuf, u16* __restrict__ outp) {
    constexpr int T = 1024, L = 2048, MM = 1024;
    __shared__ __attribute__((aligned(16))) u16 Vt[2][64][72]; // V^T tile, dbuf
    __shared__ __attribute__((aligned(16))) u16 Pl[4][16][72]; // per-wave P tile
    // XCD swizzle: all 16 i-tiles of one (b,h) land on one XCD (K/V L2-resident)
    const int bid = blockIdx.x;
    const int g = (bid & 7) + 8 * (bid >> 7);   // head-group 0..63
    const int it = (bid >> 3) & 15;
    const int h = g & 15, b = g >> 4;
    const int i0 = it * 64;
    const int tid = threadIdx.x;
    const int w = tid >> 6, l = tid & 63;
    const int lg = l >> 4, ll = l & 15;
    const int iw0 = i0 + w * 16;

    bf16x8 quf[2], qvf[2], qv2f[2];
    {
        const size_t qrow = (size_t)(b * T + iw0 + ll);
        const int qc = h * 64 + lg * 8;
        quf[0] = *(const bf16x8*)&qu[qrow * 1024 + qc];
        quf[1] = *(const bf16x8*)&qu[qrow * 1024 + qc + 32];
        qvf[0] = *(const bf16x8*)&qv[qrow * 1024 + qc];
        qvf[1] = *(const bf16x8*)&qv[qrow * 1024 + qc + 32];
        const int r2 = iw0 + ll + 1;
        const size_t qrow2 = (size_t)(b * T + (r2 < T ? r2 : T - 1));
        qv2f[0] = *(const bf16x8*)&qv[qrow2 * 1024 + qc];
        qv2f[1] = *(const bf16x8*)&qv[qrow2 * 1024 + qc + 32];
    }
    const u16* kb = kcat + (size_t)b * L * 1024 + h * 64;
    const u16* vb = vcat + (size_t)b * L * 1024 + h * 64;
    const u16* rb = rbuf + h * 64;

    f32x4 o_acc[4] = {};
    float m_run[4] = {-1e30f, -1e30f, -1e30f, -1e30f};
    float l_run[4] = {0.f, 0.f, 0.f, 0.f};
    const bf16x8 zv = {0, 0, 0, 0, 0, 0, 0, 0};
    const int vdg = tid & 15, vjq = tid >> 4;   // V-stage: d-group, j-group

    for (int jt = 0; jt < 32; ++jt) {
        const int j0 = jt * 64;
        const int buf = jt & 1;
        { // stage V^T: 4 vec loads + in-reg 4x4 transpose + 4 b64 writes
            const u16* srcv = vb + (size_t)(j0 + vjq * 4) * 1024 + vdg * 4;
            const ushort4 r0 = *(const ushort4*)(srcv);
            const ushort4 r1 = *(const ushort4*)(srcv + 1024);
            const ushort4 r2 = *(const ushort4*)(srcv + 2048);
            const ushort4 r3 = *(const ushort4*)(srcv + 3072);
            const ushort4 c0 = {r0.x, r1.x, r2.x, r3.x};
            const ushort4 c1 = {r0.y, r1.y, r2.y, r3.y};
            const ushort4 c2 = {r0.z, r1.z, r2.z, r3.z};
            const ushort4 c3 = {r0.w, r1.w, r2.w, r3.w};
            *(ushort4*)&Vt[buf][vdg * 4 + 0][vjq * 4] = c0;
            *(ushort4*)&Vt[buf][vdg * 4 + 1][vjq * 4] = c1;
            *(ushort4*)&Vt[buf][vdg * 4 + 2][vjq * 4] = c2;
            *(ushort4*)&Vt[buf][vdg * 4 + 3][vjq * 4] = c3;
        }
        __syncthreads();

        // content scores into sv
        f32x4 sv[4];
#pragma unroll
        for (int ns = 0; ns < 4; ++ns) {
            f32x4 a = {0.f, 0.f, 0.f, 0.f};
            const u16* kp = kb + (size_t)(j0 + ns * 16 + ll) * 1024 + lg * 8;
            a = mfma16(quf[0], *(const bf16x8*)kp, a);
            a = mfma16(quf[1], *(const bf16x8*)(kp + 32), a);
            sv[ns] = a;
        }

        // main band: G[i][m0+c] = qv[i].r[m0+c], fold into sv where jg <= MM+ig
        if (j0 <= MM + iw0 + 15) {
            const int m0 = j0 + T - iw0 - 16;
            f32x4 gb[5];
#pragma unroll
            for (int cs = 0; cs < 5; ++cs) {
                const int m = m0 + cs * 16 + ll;
                bf16x8 b0 = zv, b1 = zv;
                if (m >= 0 && m < L) {
                    const u16* rp = rb + (size_t)m * 1024 + lg * 8;
                    b0 = *(const bf16x8*)rp; b1 = *(const bf16x8*)(rp + 32);
                }
                f32x4 a = {0.f, 0.f, 0.f, 0.f};
                a = mfma16(qvf[0], b0, a);
                a = mfma16(qvf[1], b1, a);
                gb[cs] = a;
            }
#pragma unroll
            for (int r = 0; r < 4; ++r) {
                const int i_loc = lg * 4 + r;
                const int ig = iw0 + i_loc;
#pragma unroll
                for (int ns = 0; ns < 4; ++ns) {
                    const int j_loc = ns * 16 + ll;
                    const int c = j_loc + 15 - i_loc;
                    const int srcl = (l & 48) | (c & 15);
                    const float t0 = __shfl(gb[ns][r], srcl, 64);
                    const float t1 = __shfl(gb[ns + 1][r], srcl, 64);
                    const float gm = ((c >> 4) == ns) ? t0 : t1;
                    if (j0 + j_loc <= MM + ig) sv[ns][r] += gm;
                }
            }
        }
        // wrap band: fold where jg >= MM+ig+2 (reuses gb registers)
        if (j0 + 63 >= MM + iw0 + 2) {
            const int m0w = j0 - MM - iw0 - 17;
            f32x4 gb[5];
#pragma unroll
            for (int cs = 0; cs < 5; ++cs) {
                const int m = m0w + cs * 16 + ll;
                bf16x8 b0 = zv, b1 = zv;
                if (m >= 0 && m < L) {
                    const u16* rp = rb + (size_t)m * 1024 + lg * 8;
                    b0 = *(const bf16x8*)rp; b1 = *(const bf16x8*)(rp + 32);
                }
                f32x4 a = {0.f, 0.f, 0.f, 0.f};
                a = mfma16(qv2f[0], b0, a);
                a = mfma16(qv2f[1], b1, a);
                gb[cs] = a;
            }
#pragma unroll
            for (int r = 0; r < 4; ++r) {
                const int i_loc = lg * 4 + r;
                const int ig = iw0 + i_loc;
#pragma unroll
                for (int ns = 0; ns < 4; ++ns) {
                    const int j_loc = ns * 16 + ll;
                    const int c = j_loc + 15 - i_loc;
                    const int srcl = (l & 48) | (c & 15);
                    const float t0 = __shfl(gb[ns][r], srcl, 64);
                    const float t1 = __shfl(gb[ns + 1][r], srcl, 64);
                    const float gw = ((c >> 4) == ns) ? t0 : t1;
                    if (j0 + j_loc >= MM + ig + 2) sv[ns][r] += gw;
                }
            }
        }

        // online softmax + write P
#pragma unroll
        for (int r = 0; r < 4; ++r) {
            const int i_loc = lg * 4 + r;
            float s0 = sv[0][r] * 0.125f, s1 = sv[1][r] * 0.125f;
            float s2 = sv[2][r] * 0.125f, s3 = sv[3][r] * 0.125f;
            float pm = fmaxf(fmaxf(s0, s1), fmaxf(s2, s3));
            pm = fmaxf(pm, __shfl_xor(pm, 1, 64));
            pm = fmaxf(pm, __shfl_xor(pm, 2, 64));
            pm = fmaxf(pm, __shfl_xor(pm, 4, 64));
            pm = fmaxf(pm, __shfl_xor(pm, 8, 64));
            const float mnew = fmaxf(m_run[r], pm);
            const float alpha = __expf(m_run[r] - mnew);
            const float p0 = __expf(s0 - mnew), p1 = __expf(s1 - mnew);
            const float p2 = __expf(s2 - mnew), p3 = __expf(s3 - mnew);
            Pl[w][i_loc][0 * 16 + ll] = f2bf(p0);
            Pl[w][i_loc][1 * 16 + ll] = f2bf(p1);
            Pl[w][i_loc][2 * 16 + ll] = f2bf(p2);
            Pl[w][i_loc][3 * 16 + ll] = f2bf(p3);
            float ps = p0 + p1 + p2 + p3;
            ps += __shfl_xor(ps, 1, 64);
            ps += __shfl_xor(ps, 2, 64);
            ps += __shfl_xor(ps, 4, 64);
            ps += __shfl_xor(ps, 8, 64);
            l_run[r] = l_run[r] * alpha + ps;
            m_run[r] = mnew;
#pragma unroll
            for (int ns = 0; ns < 4; ++ns) o_acc[ns][r] *= alpha;
        }

        // O += P @ V
        const bf16x8 ap0 = *(const bf16x8*)&Pl[w][ll][lg * 8];
        const bf16x8 ap1 = *(const bf16x8*)&Pl[w][ll][32 + lg * 8];
#pragma unroll
        for (int ns = 0; ns < 4; ++ns) {
            const bf16x8 bv0 = *(const bf16x8*)&Vt[buf][ns * 16 + ll][lg * 8];
            const bf16x8 bv1 = *(const bf16x8*)&Vt[buf][ns * 16 + ll][32 + lg * 8];
            o_acc[ns] = mfma16(ap0, bv0, o_acc[ns]);
            o_acc[ns] = mfma16(ap1, bv1, o_acc[ns]);
        }
    }

#pragma unroll
    for (int ns = 0; ns < 4; ++ns)
#pragma unroll
        for (int r = 0; r < 4; ++r) {
            const int row = iw0 + lg * 4 + r;
            outp[(size_t)(b * T + row) * 1024 + h * 64 + ns * 16 + ll] =
                f2bf(o_acc[ns][r] / l_run[r]);
        }
}

// ------------------------------- launch ---------------------------------
extern "C" void kernel_launch(void* const* d_in, const int* in_sizes, int n_in,
                              void* d_out, int out_size, void* d_ws, size_t ws_size,
                              hipStream_t stream) {
    const float* x    = (const float*)d_in[0];
    const float* mem  = (const float*)d_in[1];
    const float* Wq   = (const float*)d_in[2];
    const float* Wk   = (const float*)d_in[3];
    const float* Wv   = (const float*)d_in[4];
    const float* Wr   = (const float*)d_in[5];
    const float* Wo   = (const float*)d_in[6];
    const float* bu   = (const float*)d_in[7];
    const float* bv   = (const float*)d_in[8];
    const float* ln1g = (const float*)d_in[9];
    const float* ln1b = (const float*)d_in[10];
    const float* ln2g = (const float*)d_in[11];
    const float* ln2b = (const float*)d_in[12];
    const float* W1   = (const float*)d_in[13];
    const float* b1   = (const float*)d_in[14];
    const float* W2   = (const float*)d_in[15];
    const float* b2   = (const float*)d_in[16];

    float* y_out   = (float*)d_out;             // [4,1024,1024] fp32, step 9
    float* mem_out = (float*)d_out + 4194304;   // new_mem = x (fp32), step 6.5

    // ===== d_out (32 MB fp32) as scratch, time-multiplexed =====
    char* dob = (char*)d_out;
    u16* attno = (u16*)(dob + 0);
    u16* pe    = (u16*)(dob + (size_t)8  * 1048576);
    u16* rbuf  = (u16*)(dob + (size_t)12 * 1048576);
    u16* WqT   = (u16*)(dob + (size_t)16 * 1048576);
    u16* WkT   = (u16*)(dob + (size_t)18 * 1048576);
    u16* WvT   = (u16*)(dob + (size_t)20 * 1048576);
    u16* WrT   = (u16*)(dob + (size_t)22 * 1048576);
    u16* WoT   = (u16*)(dob + (size_t)24 * 1048576);

    // ===== ws layout, extent 64 MB =====
    char* ws = (char*)d_ws;
    const size_t MB = 1u << 20;
    u16*  xn    = (u16*)(ws + 0 * MB);
    u16*  x2n   = (u16*)(ws + 0 * MB);
    u16*  W2T   = (u16*)(ws + 0 * MB);
    u16*  qu    = (u16*)(ws + 8 * MB);
    float* x2f  = (float*)(ws + 8 * MB);
    u16*  qv    = (u16*)(ws + 16 * MB);
    u16*  kcat  = (u16*)(ws + 24 * MB);
    u16*  ffh   = (u16*)(ws + 24 * MB);
    u16*  vcat  = (u16*)(ws + 40 * MB);
    u16*  memb  = (u16*)(ws + 56 * MB);
    u16*  W1T   = (u16*)(ws + 56 * MB);

    // step 1: weight transposes (fp32 -> bf16 W^T), pe, mem convert, LN1
    transpose_kernel<<<dim3(32, 32), 256, 0, stream>>>(Wq, WqT, 1024, 1024);
    transpose_kernel<<<dim3(32, 32), 256, 0, stream>>>(Wk, WkT, 1024, 1024);
    transpose_kernel<<<dim3(32, 32), 256, 0, stream>>>(Wv, WvT, 1024, 1024);
    transpose_kernel<<<dim3(32, 32), 256, 0, stream>>>(Wr, WrT, 1024, 1024);
    transpose_kernel<<<dim3(32, 32), 256, 0, stream>>>(Wo, WoT, 1024, 1024);
    pe_kernel<<<8192, 256, 0, stream>>>(pe);
    convert_kernel<<<2048, 256, 0, stream>>>(mem, memb);
    ln_kernel<<<1024, 256, 0, stream>>>(x, ln1g, ln1b, xn);
    // step 2: r = pe @ Wr
    gemm_kernel<0, false><<<dim3(16, 8), 256, 0, stream>>>(pe, nullptr, WrT, rbuf, nullptr, nullptr, nullptr, nullptr, 2048, 1024, 1024);
    // step 3: qu/qv = xn @ Wq (+bias_u / +bias_v)
    gemm_kernel<1, false><<<dim3(32, 8), 256, 0, stream>>>(xn, nullptr, WqT, qu, qv, bu, bv, nullptr, 4096, 1024, 1024);
    // step 4: k/v = [memb; xn] @ Wk/Wv
    gemm_kernel<0, true><<<dim3(64, 8), 256, 0, stream>>>(memb, xn, WkT, kcat, nullptr, nullptr, nullptr, nullptr, 8192, 1024, 1024);
    gemm_kernel<0, true><<<dim3(64, 8), 256, 0, stream>>>(memb, xn, WvT, vcat, nullptr, nullptr, nullptr, nullptr, 8192, 1024, 1024);
    // step 5: fused attention -> attno
    attn_kernel<<<1024, 256, 0, stream>>>(qu, qv, kcat, vcat, rbuf, attno);
    // step 6: x2 = x + attn @ Wo (fp32; x2f overlays dead qu/qv)
    gemm_kernel<2, false><<<dim3(32, 8), 256, 0, stream>>>(attno, nullptr, WoT, x2f, nullptr, nullptr, nullptr, x, 4096, 1024, 1024);
    // step 6.5: W1T into memb slot (memb dead); new_mem = x (fp32 copy)
    transpose_kernel<<<dim3(128, 32), 256, 0, stream>>>(W1, W1T, 1024, 4096);
    hipMemcpyAsync(mem_out, x, (size_t)4194304 * 4, hipMemcpyDeviceToDevice, stream);
    // step 7: LN2 (x2n overlays xn; xn dead)
    ln_kernel<<<1024, 256, 0, stream>>>(x2f, ln2g, ln2b, x2n);
    // step 8: ffh = gelu(x2n @ W1 + b1)  (ffh overlays dead kcat/vcat)
    gemm_kernel<3, false><<<dim3(32, 32), 256, 0, stream>>>(x2n, nullptr, W1T, ffh, nullptr, b1, nullptr, nullptr, 4096, 4096, 1024);
    // step 8.5: W2T into x2n slot (x2n dead after step 8)
    transpose_kernel<<<dim3(32, 128), 256, 0, stream>>>(W2, W2T, 4096, 1024);
    // step 9: y = x2 + ffh @ W2 + b2 (fp32 out; clobbers attno/pe/rbuf, dead)
    gemm_kernel<4, false><<<dim3(32, 8), 256, 0, stream>>>(ffh, nullptr, W2T, y_out, nullptr, b2, nullptr, x2f, 4096, 1024, 4096);
    (void)in_sizes; (void)n_in; (void)out_size; (void)ws_size;
}